// Round 1
// baseline (1388.901 us; speedup 1.0000x reference)
//
#include <hip/hip_runtime.h>

#define DIN 4096
#define DOUT 64
#define SEQ 2048
#define BK 64
#define WT_STRIDE 72  // 64 + 8 bf16 pad: row starts shift 4 banks/row -> only 2-way LDS conflicts (free)

typedef __bf16 bf16x8 __attribute__((ext_vector_type(8)));
typedef float f32x4 __attribute__((ext_vector_type(4)));

// out[row][n] = sum_k x[row][k] * W[aid[row/SEQ]][k][n]
// Block: 64 rows x 64 cols. 4 waves, each wave owns 16 rows (full N=64 via 4 MFMA n-tiles).
// x: global -> registers -> A-frag directly (no LDS; A-layout lane m=lane&15, k=quad*8+j).
// W: fp32 global -> bf16 LDS transposed wt[n][k] so B-frag is a ds_read_b128.
__global__ __launch_bounds__(256, 2)
void lora_gemm_kernel(const float* __restrict__ x,
                      const int* __restrict__ adapter_ids,
                      const float* __restrict__ weight,
                      float* __restrict__ out)
{
    __shared__ __align__(16) __bf16 wt[64 * WT_STRIDE];  // [n][k] for current K-slab

    const int bid  = blockIdx.x;        // 1024 blocks
    const int row0 = bid * 64;          // global row = b*SEQ + s; 64 | SEQ so whole block shares b
    const int b    = row0 / SEQ;
    const int aid  = adapter_ids[b];
    const float* wbase = weight + (size_t)aid * DIN * DOUT;

    const int tid  = threadIdx.x;
    const int wave = tid >> 6;
    const int lane = tid & 63;
    const int m16  = lane & 15;
    const int quad = lane >> 4;

    // this lane's x row pointer (A-fragment source), offset by quad's k-subblock
    const float* xrow = x + (size_t)(row0 + wave * 16 + m16) * DIN + quad * 8;

    f32x4 acc[4];
#pragma unroll
    for (int t = 0; t < 4; ++t) acc[t] = (f32x4)0.0f;

    // W staging pattern: thread -> (kk = p*16 + tid>>4, n4 = tid&15), float4 over n
    const int s_kk = tid >> 4;   // 0..15
    const int s_n4 = tid & 15;   // 0..15

    for (int k0 = 0; k0 < DIN; k0 += BK) {
        // stage W[aid][k0..k0+64][0..64] -> wt[n][k] (bf16, transposed)
#pragma unroll
        for (int p = 0; p < 4; ++p) {
            const int kk = p * 16 + s_kk;
            const f32x4 w4 = *(const f32x4*)(wbase + (size_t)(k0 + kk) * DOUT + s_n4 * 4);
#pragma unroll
            for (int i = 0; i < 4; ++i)
                wt[(s_n4 * 4 + i) * WT_STRIDE + kk] = (__bf16)w4[i];
        }
        __syncthreads();

#pragma unroll
        for (int ks = 0; ks < BK; ks += 32) {
            // A fragment straight from global: 8 consecutive fp32 -> bf16x8
            const f32x4 xa = *(const f32x4*)(xrow + k0 + ks);
            const f32x4 xb = *(const f32x4*)(xrow + k0 + ks + 4);
            bf16x8 a;
            a[0] = (__bf16)xa[0]; a[1] = (__bf16)xa[1];
            a[2] = (__bf16)xa[2]; a[3] = (__bf16)xa[3];
            a[4] = (__bf16)xb[0]; a[5] = (__bf16)xb[1];
            a[6] = (__bf16)xb[2]; a[7] = (__bf16)xb[3];
#pragma unroll
            for (int t = 0; t < 4; ++t) {
                const bf16x8 bf = *(const bf16x8*)(&wt[(t * 16 + m16) * WT_STRIDE + ks + quad * 8]);
                acc[t] = __builtin_amdgcn_mfma_f32_16x16x32_bf16(a, bf, acc[t], 0, 0, 0);
            }
        }
        __syncthreads();
    }

    // C/D layout: col = lane&15, row = quad*4 + reg
    float* obase = out + (size_t)(row0 + wave * 16 + quad * 4) * DOUT + m16;
#pragma unroll
    for (int i = 0; i < 4; ++i)
#pragma unroll
        for (int t = 0; t < 4; ++t)
            obase[(size_t)i * DOUT + t * 16] = acc[t][i];
}

extern "C" void kernel_launch(void* const* d_in, const int* in_sizes, int n_in,
                              void* d_out, int out_size, void* d_ws, size_t ws_size,
                              hipStream_t stream) {
    const float* x   = (const float*)d_in[0];
    const int*   ids = (const int*)d_in[1];
    const float* w   = (const float*)d_in[2];
    float* out = (float*)d_out;

    const int total_rows = 32 * SEQ;            // 65536
    dim3 grid(total_rows / 64);                 // 1024 blocks
    dim3 block(256);
    lora_gemm_kernel<<<grid, block, 0, stream>>>(x, ids, w, out);
}